// Round 12
// baseline (236.993 us; speedup 1.0000x reference)
//
#include <hip/hip_runtime.h>
#include <hip/hip_bf16.h>
#include <math.h>

#define BATCH 4
#define C 128
#define H 88
#define W 88
#define HW 7744
#define NPIX 30976   // BATCH*HW
#define HALF 44
#define HID 512

typedef __attribute__((ext_vector_type(8))) short bfrag;   // 8 x bf16 (4 VGPR)
typedef __attribute__((ext_vector_type(4))) float f32x4;

__device__ __forceinline__ short f2bf(float f) {
    union { __hip_bfloat16 b; unsigned short u; } cv;
    cv.b = __float2bfloat16(f);
    return (short)cv.u;
}
__device__ __forceinline__ float bf2f(short s) {
    union { unsigned int u; float f; } cv;
    cv.u = ((unsigned int)(unsigned short)s) << 16;
    return cv.f;
}
__device__ __forceinline__ bfrag cvt8(const float* p) {
    const float4 f0 = *(const float4*)p;
    const float4 f1 = *(const float4*)(p + 4);
    bfrag t;
    t[0] = f2bf(f0.x); t[1] = f2bf(f0.y); t[2] = f2bf(f0.z); t[3] = f2bf(f0.w);
    t[4] = f2bf(f1.x); t[5] = f2bf(f1.y); t[6] = f2bf(f1.z); t[7] = f2bf(f1.w);
    return t;
}

// bilinear 2x upsample taps (jax half-pixel, clamped)
__device__ __forceinline__ void up_taps(int i, int& j0, int& j1, float& w0, float& w1) {
    float f = 0.5f * i - 0.25f;
    int i0 = (int)floorf(f);
    float fr = f - (float)i0;
    j0 = max(i0, 0);
    j1 = min(i0 + 1, HALF - 1);
    w0 = 1.f - fr;
    w1 = fr;
}

// ---------------- K1: LN1+mask -> xnm (bf16 pixel-major); edge upsample -> e ----------------
__global__ __launch_bounds__(256) void k_pre(
    const float* __restrict__ x, const float* __restrict__ mask,
    const float* __restrict__ edge, const float* __restrict__ ln1w,
    const float* __restrict__ ln1b,
    __hip_bfloat16* __restrict__ xnm, __hip_bfloat16* __restrict__ eo)
{
    __shared__ float redS[8][32], redQ[8][32];
    const int tid = threadIdx.x, s = tid >> 5, px = tid & 31;
    const int blk = blockIdx.x, b = blk / 242, hw0 = (blk % 242) * 32;
    const int hw = hw0 + px, hi = hw / W, wi = hw % W;
    const int cs = s * 16;

    int y0, y1, x0, x1c; float wy0, wy1, wx0, wx1;
    up_taps(hi, y0, y1, wy0, wy1);
    up_taps(wi, x0, x1c, wx0, wx1);

    const float* mb = mask + (size_t)b * HALF * HALF;
    const float mval = wy0 * (wx0 * mb[y0 * HALF + x0] + wx1 * mb[y0 * HALF + x1c])
                     + wy1 * (wx0 * mb[y1 * HALF + x0] + wx1 * mb[y1 * HALF + x1c]);

    const float* xb = x + (size_t)b * C * HW;
    const float* ebs = edge + (size_t)b * C * HALF * HALF;
    float xr[16], er[16];
    float sum = 0.f, sq = 0.f;
    #pragma unroll
    for (int i = 0; i < 16; ++i) {
        const int c = cs + i;
        const float t = xb[c * HW + hw];
        xr[i] = t; sum += t; sq += t * t;
        const float* ec = ebs + c * HALF * HALF;
        er[i] = wy0 * (wx0 * ec[y0 * HALF + x0] + wx1 * ec[y0 * HALF + x1c])
              + wy1 * (wx0 * ec[y1 * HALF + x0] + wx1 * ec[y1 * HALF + x1c]);
    }
    redS[s][px] = sum; redQ[s][px] = sq;
    __syncthreads();
    float tsum = 0.f, tsq = 0.f;
    #pragma unroll
    for (int i = 0; i < 8; ++i) { tsum += redS[i][px]; tsq += redQ[i][px]; }
    const float mu = tsum * (1.f / C);
    const float rstd = rsqrtf(tsq * (1.f / C) - mu * mu + 1e-5f);

    const size_t gp = (size_t)b * HW + hw;
    bfrag r0, r1;
    #pragma unroll
    for (int i = 0; i < 8; ++i) {
        r0[i] = f2bf(((xr[i] - mu) * rstd * ln1w[cs + i] + ln1b[cs + i]) * mval);
        r1[i] = f2bf(((xr[8 + i] - mu) * rstd * ln1w[cs + 8 + i] + ln1b[cs + 8 + i]) * mval);
    }
    *(bfrag*)((short*)xnm + gp * C + cs) = r0;
    *(bfrag*)((short*)xnm + gp * C + cs + 8) = r1;
    #pragma unroll
    for (int i = 0; i < 8; ++i) { r0[i] = f2bf(er[i]); r1[i] = f2bf(er[8 + i]); }
    *(bfrag*)((short*)eo + gp * C + cs) = r0;
    *(bfrag*)((short*)eo + gp * C + cs + 8) = r1;
}

// ======= GEMMs: 512 thr = 8 waves share one LDS-staged 64-row B tile; wave = 32px x 32c =======

// ---------------- fused QKV GEMM (K=128): grid (242, 6) ----------------
__global__ __launch_bounds__(512) void k_gemmQKV(
    const __hip_bfloat16* __restrict__ eb, const __hip_bfloat16* __restrict__ xnm,
    const float* __restrict__ Wq, const float* __restrict__ Wk, const float* __restrict__ Wv,
    __hip_bfloat16* __restrict__ qb, __hip_bfloat16* __restrict__ kb,
    __hip_bfloat16* __restrict__ vb)
{
    __shared__ short Bs[64 * 136];          // 17,408 B
    const int mat = blockIdx.y >> 1;
    const int c0 = (blockIdx.y & 1) * 64;
    const __hip_bfloat16* A; const float* Wf; __hip_bfloat16* Out;
    if (mat == 0)      { A = eb;  Wf = Wq; Out = qb; }
    else if (mat == 1) { A = xnm; Wf = Wk; Out = kb; }
    else               { A = xnm; Wf = Wv; Out = vb; }

    const int tid = threadIdx.x;
    {   // stage 64 rows x 128 f32 -> bf16
        const int sr = tid & 63, sq = tid >> 6;   // row, 16-col group
        const float* wr = Wf + (size_t)(c0 + sr) * 128 + sq * 16;
        short* dstS = &Bs[sr * 136 + sq * 16];
        *(bfrag*)dstS = cvt8(wr);
        *(bfrag*)(dstS + 8) = cvt8(wr + 8);
    }
    __syncthreads();

    const int lane = tid & 63, wv = tid >> 6;
    const int wm = wv & 3, wn = wv >> 2;
    const int px0 = blockIdx.x * 128 + wm * 32;
    const int lcb = wn * 32;                 // local col base in B tile
    const int lr = lane & 15, lg = lane >> 4;
    const short* As = (const short*)A;

    f32x4 acc[2][2];
    #pragma unroll
    for (int i = 0; i < 2; ++i)
        #pragma unroll
        for (int j = 0; j < 2; ++j)
            #pragma unroll
            for (int r = 0; r < 4; ++r) acc[i][j][r] = 0.f;

    bfrag a_[4][2], b_[2][2];
    #pragma unroll
    for (int ks = 0; ks < 4; ++ks)
        #pragma unroll
        for (int mi = 0; mi < 2; ++mi)
            a_[ks][mi] = *(const bfrag*)(As + (size_t)(px0 + mi * 16 + lr) * 128 + ks * 32 + lg * 8);
    #pragma unroll
    for (int nj = 0; nj < 2; ++nj)
        b_[0][nj] = *(const bfrag*)&Bs[(lcb + nj * 16 + lr) * 136 + lg * 8];

    #pragma unroll
    for (int ks = 0; ks < 4; ++ks) {
        if (ks < 3) {
            #pragma unroll
            for (int nj = 0; nj < 2; ++nj)
                b_[(ks + 1) & 1][nj] = *(const bfrag*)&Bs[(lcb + nj * 16 + lr) * 136 + (ks + 1) * 32 + lg * 8];
        }
        #pragma unroll
        for (int mi = 0; mi < 2; ++mi)
            #pragma unroll
            for (int nj = 0; nj < 2; ++nj)
                acc[mi][nj] = __builtin_amdgcn_mfma_f32_16x16x32_bf16(a_[ks][mi], b_[ks & 1][nj], acc[mi][nj], 0, 0, 0);
    }
    short* Os = (short*)Out;
    #pragma unroll
    for (int mi = 0; mi < 2; ++mi)
        #pragma unroll
        for (int nj = 0; nj < 2; ++nj)
            #pragma unroll
            for (int r = 0; r < 4; ++r) {
                const int p = px0 + mi * 16 + lg * 4 + r;
                const int c = c0 + lcb + nj * 16 + lr;
                Os[(size_t)p * 128 + c] = f2bf(acc[mi][nj][r]);
            }
}

// ---------------- GEMM K=128 (w_in): grid (242, 8) ----------------
__global__ __launch_bounds__(512) void k_gemm128(
    const __hip_bfloat16* __restrict__ A,   // [NPIX][128] bf16
    const float* __restrict__ Wf,           // [1024][128] fp32
    __hip_bfloat16* __restrict__ Out,       // [NPIX][512] bf16
    int passMode)
{
    __shared__ short Bs[64 * 136];
    const int lc0 = blockIdx.y * 64;
    const int gc0 = (lc0 < 256) ? passMode * 256 + lc0 : 512 + passMode * 256 + (lc0 - 256);
    const int tid = threadIdx.x;
    {
        const int sr = tid & 63, sq = tid >> 6;
        const float* wr = Wf + (size_t)(gc0 + sr) * 128 + sq * 16;
        short* dstS = &Bs[sr * 136 + sq * 16];
        *(bfrag*)dstS = cvt8(wr);
        *(bfrag*)(dstS + 8) = cvt8(wr + 8);
    }
    __syncthreads();

    const int lane = tid & 63, wv = tid >> 6;
    const int wm = wv & 3, wn = wv >> 2;
    const int px0 = blockIdx.x * 128 + wm * 32;
    const int lcb = wn * 32;
    const int lr = lane & 15, lg = lane >> 4;
    const short* As = (const short*)A;

    f32x4 acc[2][2];
    #pragma unroll
    for (int i = 0; i < 2; ++i)
        #pragma unroll
        for (int j = 0; j < 2; ++j)
            #pragma unroll
            for (int r = 0; r < 4; ++r) acc[i][j][r] = 0.f;

    bfrag a_[4][2], b_[2][2];
    #pragma unroll
    for (int ks = 0; ks < 4; ++ks)
        #pragma unroll
        for (int mi = 0; mi < 2; ++mi)
            a_[ks][mi] = *(const bfrag*)(As + (size_t)(px0 + mi * 16 + lr) * 128 + ks * 32 + lg * 8);
    #pragma unroll
    for (int nj = 0; nj < 2; ++nj)
        b_[0][nj] = *(const bfrag*)&Bs[(lcb + nj * 16 + lr) * 136 + lg * 8];

    #pragma unroll
    for (int ks = 0; ks < 4; ++ks) {
        if (ks < 3) {
            #pragma unroll
            for (int nj = 0; nj < 2; ++nj)
                b_[(ks + 1) & 1][nj] = *(const bfrag*)&Bs[(lcb + nj * 16 + lr) * 136 + (ks + 1) * 32 + lg * 8];
        }
        #pragma unroll
        for (int mi = 0; mi < 2; ++mi)
            #pragma unroll
            for (int nj = 0; nj < 2; ++nj)
                acc[mi][nj] = __builtin_amdgcn_mfma_f32_16x16x32_bf16(a_[ks][mi], b_[ks & 1][nj], acc[mi][nj], 0, 0, 0);
    }
    short* Os = (short*)Out;
    #pragma unroll
    for (int mi = 0; mi < 2; ++mi)
        #pragma unroll
        for (int nj = 0; nj < 2; ++nj)
            #pragma unroll
            for (int r = 0; r < 4; ++r) {
                const int p = px0 + mi * 16 + lg * 4 + r;
                const int c = lc0 + lcb + nj * 16 + lr;
                Os[(size_t)p * 512 + c] = f2bf(acc[mi][nj][r]);
            }
}

// ---------------- Attention + LN2 fused: 512 thr = 32 px x 16 lane-groups, 32 KB LDS ----------------
__global__ __launch_bounds__(512) void k_attn2(
    const __hip_bfloat16* __restrict__ Q, const __hip_bfloat16* __restrict__ Kb,
    const __hip_bfloat16* __restrict__ Vb, const float* __restrict__ x,
    const float* __restrict__ ln2w, const float* __restrict__ ln2b,
    __hip_bfloat16* __restrict__ x1, __hip_bfloat16* __restrict__ xn2)
{
    __shared__ float smem[8192];        // exactly 32 KB: kv[64][32][4]; later vT(16KB)+red(4KB) alias into it
    float (*kv)[32][4] = reinterpret_cast<float(*)[32][4]>(smem);
    const int tid = threadIdx.x, s = tid >> 5, px = tid & 31;   // 16 groups x 32 px
    const int blk = blockIdx.x, b = blk / 242, hw0 = (blk % 242) * 32;
    const int hw = hw0 + px, hi = hw / W, wi = hw % W;
    const size_t gp = (size_t)b * HW + hw;
    const int cs = s * 8;

    {   // stage K,V (8 channels per thread) into interleaved LDS
        const short* ks_ = (const short*)Kb + gp * C + cs;
        const short* vs_ = (const short*)Vb + gp * C + cs;
        bfrag kb0 = *(const bfrag*)ks_;
        bfrag vb0 = *(const bfrag*)vs_;
        const int comp = (s < 8) ? 0 : 1;
        const int kkb = (s & 7) * 8;
        #pragma unroll
        for (int i = 0; i < 8; ++i) {
            kv[kkb + i][px][comp]     = bf2f(kb0[i]);
            kv[kkb + i][px][comp + 2] = bf2f(vb0[i]);
        }
    }
    float q1r[4], q2r[4];
    {
        const short* qs = (const short*)Q + gp * C;
        // 0.125 * log2(e): softmax via exp2 (ratios identical, one fewer VALU op per element)
        const float qscale = 0.18033688011112042f;
        #pragma unroll
        for (int rr = 0; rr < 4; ++rr) {
            const int j = s + 16 * rr;
            q1r[rr] = bf2f(qs[j]) * qscale;
            q2r[rr] = bf2f(qs[64 + j]) * qscale;
        }
    }
    __syncthreads();

    float ssum[4], o1[4], o2[4];
    #pragma unroll
    for (int rr = 0; rr < 4; ++rr) { ssum[rr] = 0.f; o1[rr] = 0.f; o2[rr] = 0.f; }

    #pragma unroll 8
    for (int kk = 0; kk < 64; ++kk) {
        const f32x4 vv = *(const f32x4*)kv[kk][px];
        #pragma unroll
        for (int rr = 0; rr < 4; ++rr) {
            const float d = q1r[rr] * vv[0] + q2r[rr] * vv[1];
            const float e = exp2f(d);   // |d| < ~0.6 by construction: no-max softmax safe
            ssum[rr] += e;
            o1[rr] += e * vv[2];
            o2[rr] += e * vv[3];
        }
    }

    const int r_ = hi >> 2, col = wi >> 2, n = (hi & 3) * 4 + (wi & 3);
    const size_t bbase = (size_t)b * C * HW;
    const int wbase = r_ * 22 + col;
    float v1r[4], v2r[4];
    float sum = 0.f, sq = 0.f;
    #pragma unroll
    for (int rr = 0; rr < 4; ++rr) {
        const int j = s + 16 * rr;
        const float inv = 1.f / ssum[rr];
        const int f1 = (n * C + j) * 484 + wbase;
        const int f2 = (n * C + 64 + j) * 484 + wbase;
        const float v1 = x[bbase + f1] + o1[rr] * inv;
        const float v2 = x[bbase + f2] + o2[rr] * inv;
        x1[bbase + f1] = __float2bfloat16(v1);
        x1[bbase + f2] = __float2bfloat16(v2);
        v1r[rr] = v1; v2r[rr] = v2;
        sum += v1 + v2; sq += v1 * v1 + v2 * v2;
    }
    __syncthreads();   // all waves done reading kv — safe to alias vT/red into smem
    float (*vT)[32]   = reinterpret_cast<float(*)[32]>(smem);          // 128*32 = 4096 floats
    float (*redS)[32] = reinterpret_cast<float(*)[32]>(smem + 4096);   // 16*32 = 512
    float (*redQ)[32] = reinterpret_cast<float(*)[32]>(smem + 4608);   // 16*32 = 512 (ends 5120 < 8192)
    #pragma unroll
    for (int rr = 0; rr < 4; ++rr) {
        const int j = s + 16 * rr;
        vT[j][px] = v1r[rr];
        vT[64 + j][px] = v2r[rr];
    }
    redS[s][px] = sum; redQ[s][px] = sq;
    __syncthreads();
    float tsum = 0.f, tsq = 0.f;
    #pragma unroll
    for (int i = 0; i < 16; ++i) { tsum += redS[i][px]; tsq += redQ[i][px]; }
    const float mu = tsum * (1.f / C);
    const float rstd = rsqrtf(tsq * (1.f / C) - mu * mu + 1e-5f);
    bfrag r0;
    #pragma unroll
    for (int i = 0; i < 8; ++i)
        r0[i] = f2bf((vT[cs + i][px] - mu) * rstd * ln2w[cs + i] + ln2b[cs + i]);
    *(bfrag*)((short*)xn2 + gp * C + cs) = r0;
}

// ---------------- depthwise 3x3 + gelu gate, parallel rolling-window version ----------------
__global__ __launch_bounds__(256) void k_dw(
    const __hip_bfloat16* __restrict__ U,   // [NPIX][512] (t1: cols 0..255, t2: 256..511)
    const float* __restrict__ wdw,          // [1024][9]
    __hip_bfloat16* __restrict__ Gout,      // [NPIX][512]
    int pass)
{
    const int cl = threadIdx.x;
    const int blk = blockIdx.x;             // b*H*11 + hi*11 + seg
    const int seg = blk % 11;
    const int hi = (blk / 11) % H;
    const int b = blk / (11 * H);
    const int w0 = seg * 8;
    const int gc1 = pass * 256 + cl, gc2 = 512 + gc1;

    float w1[9], w2[9];
    #pragma unroll
    for (int t = 0; t < 9; ++t) { w1[t] = wdw[gc1 * 9 + t]; w2[t] = wdw[gc2 * 9 + t]; }

    const short* Us = (const short*)U;
    const size_t base = (size_t)b * HW;
    const bool r0ok = (hi - 1) >= 0, r2ok = (hi + 1) < H;

    float A1[3][3], A2[3][3];

    #define LOADCOL(slot, wc)  do {                                              \
        if ((unsigned)(wc) >= W) {                                               \
            A1[slot][0]=A1[slot][1]=A1[slot][2]=0.f;                             \
            A2[slot][0]=A2[slot][1]=A2[slot][2]=0.f;                             \
        } else {                                                                 \
            size_t p1 = base + (size_t)(hi - 1) * W + (wc);                      \
            size_t p2 = base + (size_t)hi * W + (wc);                            \
            size_t p3 = base + (size_t)(hi + 1) * W + (wc);                      \
            A1[slot][0] = r0ok ? bf2f(Us[p1 * 512 + cl]) : 0.f;                  \
            A2[slot][0] = r0ok ? bf2f(Us[p1 * 512 + 256 + cl]) : 0.f;            \
            A1[slot][1] = bf2f(Us[p2 * 512 + cl]);                               \
            A2[slot][1] = bf2f(Us[p2 * 512 + 256 + cl]);                         \
            A1[slot][2] = r2ok ? bf2f(Us[p3 * 512 + cl]) : 0.f;                  \
            A2[slot][2] = r2ok ? bf2f(Us[p3 * 512 + 256 + cl]) : 0.f;            \
        } } while (0)

    LOADCOL(0, w0 - 1);
    LOADCOL(1, w0);

    #pragma unroll
    for (int i = 0; i < 8; ++i) {
        const int wi = w0 + i;
        const int sl = i % 3, sm = (i + 1) % 3, sr = (i + 2) % 3;
        LOADCOL(sr, wi + 1);
        float t1 = 0.f, t2 = 0.f;
        #pragma unroll
        for (int r = 0; r < 3; ++r) {
            t1 += w1[r * 3 + 0] * A1[sl][r] + w1[r * 3 + 1] * A1[sm][r] + w1[r * 3 + 2] * A1[sr][r];
            t2 += w2[r * 3 + 0] * A2[sl][r] + w2[r * 3 + 1] * A2[sm][r] + w2[r * 3 + 2] * A2[sr][r];
        }
        const float gl = 0.5f * t1 * (1.f + erff(t1 * 0.70710678118654752f));
        Gout[(base + (size_t)hi * W + wi) * 512 + pass * 256 + cl] = __float2bfloat16(gl * t2);
    }
    #undef LOADCOL
}

// ---------------- GEMM K=512 + residual: grid (242, 2), 64-row B tile ----------------
__global__ __launch_bounds__(512) void k_gemm512(
    const __hip_bfloat16* __restrict__ G,   // [NPIX][512]
    const float* __restrict__ Wof,          // [128][512] f32
    const __hip_bfloat16* __restrict__ X1,  // [B][C][HW] bf16
    float* __restrict__ Outp)               // [B][C][HW] f32
{
    __shared__ short Bs[64 * 520];          // 66,560 B
    const int c0 = blockIdx.y * 64;
    const int tid = threadIdx.x;
    {   // stage 64 rows x 512 f32 -> bf16
        const int sr = tid & 63, sq = tid >> 6;   // row, 64-col group
        const float* wr = Wof + (size_t)(c0 + sr) * 512 + sq * 64;
        short* dstS = &Bs[sr * 520 + sq * 64];
        #pragma unroll
        for (int i8 = 0; i8 < 8; ++i8)
            *(bfrag*)(dstS + i8 * 8) = cvt8(wr + i8 * 8);
    }
    __syncthreads();

    const int lane = tid & 63, wv = tid >> 6;
    const int wm = wv & 3, wn = wv >> 2;
    const int px0 = blockIdx.x * 128 + wm * 32;
    const int lcb = wn * 32;
    const int lr = lane & 15, lg = lane >> 4;
    const short* Gs = (const short*)G;

    f32x4 acc[2][2];
    #pragma unroll
    for (int i = 0; i < 2; ++i)
        #pragma unroll
        for (int j = 0; j < 2; ++j)
            #pragma unroll
            for (int r = 0; r < 4; ++r) acc[i][j][r] = 0.f;

    bfrag a_[4][2], b_[2][2];
    #pragma unroll
    for (int ks = 0; ks < 4; ++ks)
        #pragma unroll
        for (int mi = 0; mi < 2; ++mi)
            a_[ks][mi] = *(const bfrag*)(Gs + (size_t)(px0 + mi * 16 + lr) * 512 + ks * 32 + lg * 8);
    #pragma unroll
    for (int nj = 0; nj < 2; ++nj)
        b_[0][nj] = *(const bfrag*)&Bs[(lcb + nj * 16 + lr) * 520 + lg * 8];

    #pragma unroll
    for (int ks = 0; ks < 16; ++ks) {
        if (ks < 15) {
            #pragma unroll
            for (int nj = 0; nj < 2; ++nj)
                b_[(ks + 1) & 1][nj] = *(const bfrag*)&Bs[(lcb + nj * 16 + lr) * 520 + (ks + 1) * 32 + lg * 8];
        }
        if (ks < 12) {
            #pragma unroll
            for (int mi = 0; mi < 2; ++mi)
                a_[(ks + 4) & 3][mi] = *(const bfrag*)(Gs + (size_t)(px0 + mi * 16 + lr) * 512 + (ks + 4) * 32 + lg * 8);
        }
        #pragma unroll
        for (int mi = 0; mi < 2; ++mi)
            #pragma unroll
            for (int nj = 0; nj < 2; ++nj)
                acc[mi][nj] = __builtin_amdgcn_mfma_f32_16x16x32_bf16(a_[ks & 3][mi], b_[ks & 1][nj], acc[mi][nj], 0, 0, 0);
    }

    #pragma unroll
    for (int mi = 0; mi < 2; ++mi)
        #pragma unroll
        for (int nj = 0; nj < 2; ++nj)
            #pragma unroll
            for (int r = 0; r < 4; ++r) {
                const int p = px0 + mi * 16 + lg * 4 + r;
                const int c = c0 + lcb + nj * 16 + lr;
                const int b = p / HW, hw = p % HW;
                const size_t idx = ((size_t)b * C + c) * HW + hw;
                Outp[idx] = __bfloat162float(X1[idx]) + acc[mi][nj][r];
            }
}

extern "C" void kernel_launch(void* const* d_in, const int* in_sizes, int n_in,
                              void* d_out, int out_size, void* d_ws, size_t ws_size,
                              hipStream_t stream) {
    (void)in_sizes; (void)n_in; (void)out_size; (void)ws_size;
    const float* x     = (const float*)d_in[0];
    const float* mask  = (const float*)d_in[1];
    const float* edge  = (const float*)d_in[2];
    const float* ln1w  = (const float*)d_in[3];
    const float* ln1b  = (const float*)d_in[4];
    const float* Wq    = (const float*)d_in[5];
    const float* Wk    = (const float*)d_in[6];
    const float* Wv    = (const float*)d_in[7];
    const float* ln2w  = (const float*)d_in[8];
    const float* ln2b  = (const float*)d_in[9];
    const float* w_in  = (const float*)d_in[10];
    const float* w_dw  = (const float*)d_in[11];
    const float* w_out = (const float*)d_in[12];
    float* out = (float*)d_out;

    char* ws = (char*)d_ws;
    // persistent: [0, 7.93M) x1 bf16 ; [7.93M, 15.86M) xn2 bf16 ;
    // [15.86M, 47.58M) u_half bf16 ; [47.58M, 79.30M) g bf16. Total = 79,298,560 B.
    __hip_bfloat16* x1  = (__hip_bfloat16*)(ws + 0);
    __hip_bfloat16* xn2 = (__hip_bfloat16*)(ws + 7929856);
    __hip_bfloat16* uh  = (__hip_bfloat16*)(ws + 15859712);
    __hip_bfloat16* g   = (__hip_bfloat16*)(ws + 47579136);
    // transient (dead before u_half/g are written):
    __hip_bfloat16* qb  = (__hip_bfloat16*)(ws + 15859712);
    __hip_bfloat16* kb  = (__hip_bfloat16*)(ws + 23789568);
    __hip_bfloat16* vb  = (__hip_bfloat16*)(ws + 31719424);
    __hip_bfloat16* eb  = (__hip_bfloat16*)(ws + 39649280);
    __hip_bfloat16* xnm = (__hip_bfloat16*)(ws + 47579136);

    k_pre<<<968, 256, 0, stream>>>(x, mask, edge, ln1w, ln1b, xnm, eb);
    k_gemmQKV<<<dim3(242, 6), 512, 0, stream>>>(eb, xnm, Wq, Wk, Wv, qb, kb, vb);
    k_attn2<<<968, 512, 0, stream>>>(qb, kb, vb, x, ln2w, ln2b, x1, xn2);
    k_gemm128<<<dim3(242, 8), 512, 0, stream>>>(xn2, w_in, uh, 0);
    k_dw<<<3872, 256, 0, stream>>>(uh, w_dw, g, 0);
    k_gemm128<<<dim3(242, 8), 512, 0, stream>>>(xn2, w_in, uh, 1);
    k_dw<<<3872, 256, 0, stream>>>(uh, w_dw, g, 1);
    k_gemm512<<<dim3(242, 2), 512, 0, stream>>>(g, w_out, x1, out);
}

// Round 13
// 222.054 us; speedup vs baseline: 1.0673x; 1.0673x over previous
//
#include <hip/hip_runtime.h>
#include <hip/hip_bf16.h>
#include <math.h>

#define BATCH 4
#define C 128
#define H 88
#define W 88
#define HW 7744
#define NPIX 30976   // BATCH*HW
#define HALF 44
#define HID 512

// native exp2 if available (single v_exp_f32); else __expf (v_mul+v_exp)
#if defined(__has_builtin)
#  if __has_builtin(__builtin_amdgcn_exp2f)
#    define EXP_FAST(x) __builtin_amdgcn_exp2f(x)
#    define QSCALE 0.18033688011112042f   /* 0.125 * log2(e) */
#  endif
#endif
#ifndef EXP_FAST
#  define EXP_FAST(x) __expf(x)
#  define QSCALE 0.125f
#endif

typedef __attribute__((ext_vector_type(8))) short bfrag;   // 8 x bf16 (4 VGPR)
typedef __attribute__((ext_vector_type(4))) float f32x4;

__device__ __forceinline__ short f2bf(float f) {
    union { __hip_bfloat16 b; unsigned short u; } cv;
    cv.b = __float2bfloat16(f);
    return (short)cv.u;
}
__device__ __forceinline__ float bf2f(short s) {
    union { unsigned int u; float f; } cv;
    cv.u = ((unsigned int)(unsigned short)s) << 16;
    return cv.f;
}
__device__ __forceinline__ bfrag cvt8(const float* p) {
    const float4 f0 = *(const float4*)p;
    const float4 f1 = *(const float4*)(p + 4);
    bfrag t;
    t[0] = f2bf(f0.x); t[1] = f2bf(f0.y); t[2] = f2bf(f0.z); t[3] = f2bf(f0.w);
    t[4] = f2bf(f1.x); t[5] = f2bf(f1.y); t[6] = f2bf(f1.z); t[7] = f2bf(f1.w);
    return t;
}

// bilinear 2x upsample taps (jax half-pixel, clamped)
__device__ __forceinline__ void up_taps(int i, int& j0, int& j1, float& w0, float& w1) {
    float f = 0.5f * i - 0.25f;
    int i0 = (int)floorf(f);
    float fr = f - (float)i0;
    j0 = max(i0, 0);
    j1 = min(i0 + 1, HALF - 1);
    w0 = 1.f - fr;
    w1 = fr;
}

// ---------------- K1: LN1+mask -> xnm (bf16 pixel-major); edge upsample -> e ----------------
__global__ __launch_bounds__(256) void k_pre(
    const float* __restrict__ x, const float* __restrict__ mask,
    const float* __restrict__ edge, const float* __restrict__ ln1w,
    const float* __restrict__ ln1b,
    __hip_bfloat16* __restrict__ xnm, __hip_bfloat16* __restrict__ eo)
{
    __shared__ float redS[8][32], redQ[8][32];
    const int tid = threadIdx.x, s = tid >> 5, px = tid & 31;
    const int blk = blockIdx.x, b = blk / 242, hw0 = (blk % 242) * 32;
    const int hw = hw0 + px, hi = hw / W, wi = hw % W;
    const int cs = s * 16;

    int y0, y1, x0, x1c; float wy0, wy1, wx0, wx1;
    up_taps(hi, y0, y1, wy0, wy1);
    up_taps(wi, x0, x1c, wx0, wx1);

    const float* mb = mask + (size_t)b * HALF * HALF;
    const float mval = wy0 * (wx0 * mb[y0 * HALF + x0] + wx1 * mb[y0 * HALF + x1c])
                     + wy1 * (wx0 * mb[y1 * HALF + x0] + wx1 * mb[y1 * HALF + x1c]);

    const float* xb = x + (size_t)b * C * HW;
    const float* ebs = edge + (size_t)b * C * HALF * HALF;
    float xr[16], er[16];
    float sum = 0.f, sq = 0.f;
    #pragma unroll
    for (int i = 0; i < 16; ++i) {
        const int c = cs + i;
        const float t = xb[c * HW + hw];
        xr[i] = t; sum += t; sq += t * t;
        const float* ec = ebs + c * HALF * HALF;
        er[i] = wy0 * (wx0 * ec[y0 * HALF + x0] + wx1 * ec[y0 * HALF + x1c])
              + wy1 * (wx0 * ec[y1 * HALF + x0] + wx1 * ec[y1 * HALF + x1c]);
    }
    redS[s][px] = sum; redQ[s][px] = sq;
    __syncthreads();
    float tsum = 0.f, tsq = 0.f;
    #pragma unroll
    for (int i = 0; i < 8; ++i) { tsum += redS[i][px]; tsq += redQ[i][px]; }
    const float mu = tsum * (1.f / C);
    const float rstd = rsqrtf(tsq * (1.f / C) - mu * mu + 1e-5f);

    const size_t gp = (size_t)b * HW + hw;
    bfrag r0, r1;
    #pragma unroll
    for (int i = 0; i < 8; ++i) {
        r0[i] = f2bf(((xr[i] - mu) * rstd * ln1w[cs + i] + ln1b[cs + i]) * mval);
        r1[i] = f2bf(((xr[8 + i] - mu) * rstd * ln1w[cs + 8 + i] + ln1b[cs + 8 + i]) * mval);
    }
    *(bfrag*)((short*)xnm + gp * C + cs) = r0;
    *(bfrag*)((short*)xnm + gp * C + cs + 8) = r1;
    #pragma unroll
    for (int i = 0; i < 8; ++i) { r0[i] = f2bf(er[i]); r1[i] = f2bf(er[8 + i]); }
    *(bfrag*)((short*)eo + gp * C + cs) = r0;
    *(bfrag*)((short*)eo + gp * C + cs + 8) = r1;
}

// ======= GEMMs: 512 thr = 8 waves share one LDS-staged 64-row B tile; wave = 32px x 32c =======

// ---------------- fused QKV GEMM (K=128): grid (242, 6) ----------------
__global__ __launch_bounds__(512) void k_gemmQKV(
    const __hip_bfloat16* __restrict__ eb, const __hip_bfloat16* __restrict__ xnm,
    const float* __restrict__ Wq, const float* __restrict__ Wk, const float* __restrict__ Wv,
    __hip_bfloat16* __restrict__ qb, __hip_bfloat16* __restrict__ kb,
    __hip_bfloat16* __restrict__ vb)
{
    __shared__ short Bs[64 * 136];          // 17,408 B
    const int mat = blockIdx.y >> 1;
    const int c0 = (blockIdx.y & 1) * 64;
    const __hip_bfloat16* A; const float* Wf; __hip_bfloat16* Out;
    if (mat == 0)      { A = eb;  Wf = Wq; Out = qb; }
    else if (mat == 1) { A = xnm; Wf = Wk; Out = kb; }
    else               { A = xnm; Wf = Wv; Out = vb; }

    const int tid = threadIdx.x;
    {   // stage 64 rows x 128 f32 -> bf16
        const int sr = tid & 63, sq = tid >> 6;   // row, 16-col group
        const float* wr = Wf + (size_t)(c0 + sr) * 128 + sq * 16;
        short* dstS = &Bs[sr * 136 + sq * 16];
        *(bfrag*)dstS = cvt8(wr);
        *(bfrag*)(dstS + 8) = cvt8(wr + 8);
    }
    __syncthreads();

    const int lane = tid & 63, wv = tid >> 6;
    const int wm = wv & 3, wn = wv >> 2;
    const int px0 = blockIdx.x * 128 + wm * 32;
    const int lcb = wn * 32;                 // local col base in B tile
    const int lr = lane & 15, lg = lane >> 4;
    const short* As = (const short*)A;

    f32x4 acc[2][2];
    #pragma unroll
    for (int i = 0; i < 2; ++i)
        #pragma unroll
        for (int j = 0; j < 2; ++j)
            #pragma unroll
            for (int r = 0; r < 4; ++r) acc[i][j][r] = 0.f;

    bfrag a_[4][2], b_[2][2];
    #pragma unroll
    for (int ks = 0; ks < 4; ++ks)
        #pragma unroll
        for (int mi = 0; mi < 2; ++mi)
            a_[ks][mi] = *(const bfrag*)(As + (size_t)(px0 + mi * 16 + lr) * 128 + ks * 32 + lg * 8);
    #pragma unroll
    for (int nj = 0; nj < 2; ++nj)
        b_[0][nj] = *(const bfrag*)&Bs[(lcb + nj * 16 + lr) * 136 + lg * 8];

    #pragma unroll
    for (int ks = 0; ks < 4; ++ks) {
        if (ks < 3) {
            #pragma unroll
            for (int nj = 0; nj < 2; ++nj)
                b_[(ks + 1) & 1][nj] = *(const bfrag*)&Bs[(lcb + nj * 16 + lr) * 136 + (ks + 1) * 32 + lg * 8];
        }
        #pragma unroll
        for (int mi = 0; mi < 2; ++mi)
            #pragma unroll
            for (int nj = 0; nj < 2; ++nj)
                acc[mi][nj] = __builtin_amdgcn_mfma_f32_16x16x32_bf16(a_[ks][mi], b_[ks & 1][nj], acc[mi][nj], 0, 0, 0);
    }
    short* Os = (short*)Out;
    #pragma unroll
    for (int mi = 0; mi < 2; ++mi)
        #pragma unroll
        for (int nj = 0; nj < 2; ++nj)
            #pragma unroll
            for (int r = 0; r < 4; ++r) {
                const int p = px0 + mi * 16 + lg * 4 + r;
                const int c = c0 + lcb + nj * 16 + lr;
                Os[(size_t)p * 128 + c] = f2bf(acc[mi][nj][r]);
            }
}

// ---------------- GEMM K=128 (w_in): grid (242, 8) ----------------
__global__ __launch_bounds__(512) void k_gemm128(
    const __hip_bfloat16* __restrict__ A,   // [NPIX][128] bf16
    const float* __restrict__ Wf,           // [1024][128] fp32
    __hip_bfloat16* __restrict__ Out,       // [NPIX][512] bf16
    int passMode)
{
    __shared__ short Bs[64 * 136];
    const int lc0 = blockIdx.y * 64;
    const int gc0 = (lc0 < 256) ? passMode * 256 + lc0 : 512 + passMode * 256 + (lc0 - 256);
    const int tid = threadIdx.x;
    {
        const int sr = tid & 63, sq = tid >> 6;
        const float* wr = Wf + (size_t)(gc0 + sr) * 128 + sq * 16;
        short* dstS = &Bs[sr * 136 + sq * 16];
        *(bfrag*)dstS = cvt8(wr);
        *(bfrag*)(dstS + 8) = cvt8(wr + 8);
    }
    __syncthreads();

    const int lane = tid & 63, wv = tid >> 6;
    const int wm = wv & 3, wn = wv >> 2;
    const int px0 = blockIdx.x * 128 + wm * 32;
    const int lcb = wn * 32;
    const int lr = lane & 15, lg = lane >> 4;
    const short* As = (const short*)A;

    f32x4 acc[2][2];
    #pragma unroll
    for (int i = 0; i < 2; ++i)
        #pragma unroll
        for (int j = 0; j < 2; ++j)
            #pragma unroll
            for (int r = 0; r < 4; ++r) acc[i][j][r] = 0.f;

    bfrag a_[4][2], b_[2][2];
    #pragma unroll
    for (int ks = 0; ks < 4; ++ks)
        #pragma unroll
        for (int mi = 0; mi < 2; ++mi)
            a_[ks][mi] = *(const bfrag*)(As + (size_t)(px0 + mi * 16 + lr) * 128 + ks * 32 + lg * 8);
    #pragma unroll
    for (int nj = 0; nj < 2; ++nj)
        b_[0][nj] = *(const bfrag*)&Bs[(lcb + nj * 16 + lr) * 136 + lg * 8];

    #pragma unroll
    for (int ks = 0; ks < 4; ++ks) {
        if (ks < 3) {
            #pragma unroll
            for (int nj = 0; nj < 2; ++nj)
                b_[(ks + 1) & 1][nj] = *(const bfrag*)&Bs[(lcb + nj * 16 + lr) * 136 + (ks + 1) * 32 + lg * 8];
        }
        #pragma unroll
        for (int mi = 0; mi < 2; ++mi)
            #pragma unroll
            for (int nj = 0; nj < 2; ++nj)
                acc[mi][nj] = __builtin_amdgcn_mfma_f32_16x16x32_bf16(a_[ks][mi], b_[ks & 1][nj], acc[mi][nj], 0, 0, 0);
    }
    short* Os = (short*)Out;
    #pragma unroll
    for (int mi = 0; mi < 2; ++mi)
        #pragma unroll
        for (int nj = 0; nj < 2; ++nj)
            #pragma unroll
            for (int r = 0; r < 4; ++r) {
                const int p = px0 + mi * 16 + lg * 4 + r;
                const int c = lc0 + lcb + nj * 16 + lr;
                Os[(size_t)p * 512 + c] = f2bf(acc[mi][nj][r]);
            }
}

// ---------------- Attention + LN2 fused: 512 thr = 32 px x 16 lane-groups ----------------
__global__ __launch_bounds__(512) void k_attn2(
    const __hip_bfloat16* __restrict__ Q, const __hip_bfloat16* __restrict__ Kb,
    const __hip_bfloat16* __restrict__ Vb, const float* __restrict__ x,
    const float* __restrict__ ln2w, const float* __restrict__ ln2b,
    __hip_bfloat16* __restrict__ x1, __hip_bfloat16* __restrict__ xn2)
{
    __shared__ float kv[64][32][4];     // 32 KB; reused as vT[128][32] (16 KB) after kk-loop
    __shared__ float redS[16][32], redQ[16][32];  // 4 KB
    const int tid = threadIdx.x, s = tid >> 5, px = tid & 31;   // 16 groups x 32 px
    const int blk = blockIdx.x, b = blk / 242, hw0 = (blk % 242) * 32;
    const int hw = hw0 + px, hi = hw / W, wi = hw % W;
    const size_t gp = (size_t)b * HW + hw;
    const int cs = s * 8;

    {   // stage K,V (8 channels per thread) into interleaved LDS
        const short* ks_ = (const short*)Kb + gp * C + cs;
        const short* vs_ = (const short*)Vb + gp * C + cs;
        bfrag kb0 = *(const bfrag*)ks_;
        bfrag vb0 = *(const bfrag*)vs_;
        const int comp = (s < 8) ? 0 : 1;
        const int kkb = (s & 7) * 8;
        #pragma unroll
        for (int i = 0; i < 8; ++i) {
            kv[kkb + i][px][comp]     = bf2f(kb0[i]);
            kv[kkb + i][px][comp + 2] = bf2f(vb0[i]);
        }
    }
    float q1r[4], q2r[4];
    {
        const short* qs = (const short*)Q + gp * C;
        #pragma unroll
        for (int rr = 0; rr < 4; ++rr) {
            const int j = s + 16 * rr;
            q1r[rr] = bf2f(qs[j]) * QSCALE;
            q2r[rr] = bf2f(qs[64 + j]) * QSCALE;
        }
    }
    __syncthreads();

    float ssum[4], o1[4], o2[4];
    #pragma unroll
    for (int rr = 0; rr < 4; ++rr) { ssum[rr] = 0.f; o1[rr] = 0.f; o2[rr] = 0.f; }

    #pragma unroll 8
    for (int kk = 0; kk < 64; ++kk) {
        const f32x4 vv = *(const f32x4*)kv[kk][px];
        #pragma unroll
        for (int rr = 0; rr < 4; ++rr) {
            const float d = q1r[rr] * vv[0] + q2r[rr] * vv[1];
            const float e = EXP_FAST(d);   // |d| < ~0.6 by construction: no-max softmax safe
            ssum[rr] += e;
            o1[rr] += e * vv[2];
            o2[rr] += e * vv[3];
        }
    }

    const int r_ = hi >> 2, col = wi >> 2, n = (hi & 3) * 4 + (wi & 3);
    const size_t bbase = (size_t)b * C * HW;
    const int wbase = r_ * 22 + col;
    float v1r[4], v2r[4];
    float sum = 0.f, sq = 0.f;
    #pragma unroll
    for (int rr = 0; rr < 4; ++rr) {
        const int j = s + 16 * rr;
        const float inv = 1.f / ssum[rr];
        const int f1 = (n * C + j) * 484 + wbase;
        const int f2 = (n * C + 64 + j) * 484 + wbase;
        const float v1 = x[bbase + f1] + o1[rr] * inv;
        const float v2 = x[bbase + f2] + o2[rr] * inv;
        x1[bbase + f1] = __float2bfloat16(v1);
        x1[bbase + f2] = __float2bfloat16(v2);
        v1r[rr] = v1; v2r[rr] = v2;
        sum += v1 + v2; sq += v1 * v1 + v2 * v2;
    }
    __syncthreads();   // all waves done reading kv — safe to reuse as vT
    float (*vT)[32] = reinterpret_cast<float(*)[32]>(&kv[0][0][0]);
    #pragma unroll
    for (int rr = 0; rr < 4; ++rr) {
        const int j = s + 16 * rr;
        vT[j][px] = v1r[rr];
        vT[64 + j][px] = v2r[rr];
    }
    redS[s][px] = sum; redQ[s][px] = sq;
    __syncthreads();
    float tsum = 0.f, tsq = 0.f;
    #pragma unroll
    for (int i = 0; i < 16; ++i) { tsum += redS[i][px]; tsq += redQ[i][px]; }
    const float mu = tsum * (1.f / C);
    const float rstd = rsqrtf(tsq * (1.f / C) - mu * mu + 1e-5f);
    bfrag r0;
    #pragma unroll
    for (int i = 0; i < 8; ++i)
        r0[i] = f2bf((vT[cs + i][px] - mu) * rstd * ln2w[cs + i] + ln2b[cs + i]);
    *(bfrag*)((short*)xn2 + gp * C + cs) = r0;
}

// ---------------- depthwise 3x3 + gelu gate, parallel rolling-window version ----------------
__global__ __launch_bounds__(256) void k_dw(
    const __hip_bfloat16* __restrict__ U,   // [NPIX][512] (t1: cols 0..255, t2: 256..511)
    const float* __restrict__ wdw,          // [1024][9]
    __hip_bfloat16* __restrict__ Gout,      // [NPIX][512]
    int pass)
{
    const int cl = threadIdx.x;
    const int blk = blockIdx.x;             // b*H*11 + hi*11 + seg
    const int seg = blk % 11;
    const int hi = (blk / 11) % H;
    const int b = blk / (11 * H);
    const int w0 = seg * 8;
    const int gc1 = pass * 256 + cl, gc2 = 512 + gc1;

    float w1[9], w2[9];
    #pragma unroll
    for (int t = 0; t < 9; ++t) { w1[t] = wdw[gc1 * 9 + t]; w2[t] = wdw[gc2 * 9 + t]; }

    const short* Us = (const short*)U;
    const size_t base = (size_t)b * HW;
    const bool r0ok = (hi - 1) >= 0, r2ok = (hi + 1) < H;

    float A1[3][3], A2[3][3];

    #define LOADCOL(slot, wc)  do {                                              \
        if ((unsigned)(wc) >= W) {                                               \
            A1[slot][0]=A1[slot][1]=A1[slot][2]=0.f;                             \
            A2[slot][0]=A2[slot][1]=A2[slot][2]=0.f;                             \
        } else {                                                                 \
            size_t p1 = base + (size_t)(hi - 1) * W + (wc);                      \
            size_t p2 = base + (size_t)hi * W + (wc);                            \
            size_t p3 = base + (size_t)(hi + 1) * W + (wc);                      \
            A1[slot][0] = r0ok ? bf2f(Us[p1 * 512 + cl]) : 0.f;                  \
            A2[slot][0] = r0ok ? bf2f(Us[p1 * 512 + 256 + cl]) : 0.f;            \
            A1[slot][1] = bf2f(Us[p2 * 512 + cl]);                               \
            A2[slot][1] = bf2f(Us[p2 * 512 + 256 + cl]);                         \
            A1[slot][2] = r2ok ? bf2f(Us[p3 * 512 + cl]) : 0.f;                  \
            A2[slot][2] = r2ok ? bf2f(Us[p3 * 512 + 256 + cl]) : 0.f;            \
        } } while (0)

    LOADCOL(0, w0 - 1);
    LOADCOL(1, w0);

    #pragma unroll
    for (int i = 0; i < 8; ++i) {
        const int wi = w0 + i;
        const int sl = i % 3, sm = (i + 1) % 3, sr = (i + 2) % 3;
        LOADCOL(sr, wi + 1);
        float t1 = 0.f, t2 = 0.f;
        #pragma unroll
        for (int r = 0; r < 3; ++r) {
            t1 += w1[r * 3 + 0] * A1[sl][r] + w1[r * 3 + 1] * A1[sm][r] + w1[r * 3 + 2] * A1[sr][r];
            t2 += w2[r * 3 + 0] * A2[sl][r] + w2[r * 3 + 1] * A2[sm][r] + w2[r * 3 + 2] * A2[sr][r];
        }
        const float gl = 0.5f * t1 * (1.f + erff(t1 * 0.70710678118654752f));
        Gout[(base + (size_t)hi * W + wi) * 512 + pass * 256 + cl] = __float2bfloat16(gl * t2);
    }
    #undef LOADCOL
}

// ---------------- GEMM K=512 + residual: grid (242, 2), 64-row B tile ----------------
__global__ __launch_bounds__(512) void k_gemm512(
    const __hip_bfloat16* __restrict__ G,   // [NPIX][512]
    const float* __restrict__ Wof,          // [128][512] f32
    const __hip_bfloat16* __restrict__ X1,  // [B][C][HW] bf16
    float* __restrict__ Outp)               // [B][C][HW] f32
{
    __shared__ short Bs[64 * 520];          // 66,560 B
    const int c0 = blockIdx.y * 64;
    const int tid = threadIdx.x;
    {   // stage 64 rows x 512 f32 -> bf16
        const int sr = tid & 63, sq = tid >> 6;   // row, 64-col group
        const float* wr = Wof + (size_t)(c0 + sr) * 512 + sq * 64;
        short* dstS = &Bs[sr * 520 + sq * 64];
        #pragma unroll
        for (int i8 = 0; i8 < 8; ++i8)
            *(bfrag*)(dstS + i8 * 8) = cvt8(wr + i8 * 8);
    }
    __syncthreads();

    const int lane = tid & 63, wv = tid >> 6;
    const int wm = wv & 3, wn = wv >> 2;
    const int px0 = blockIdx.x * 128 + wm * 32;
    const int lcb = wn * 32;
    const int lr = lane & 15, lg = lane >> 4;
    const short* Gs = (const short*)G;

    f32x4 acc[2][2];
    #pragma unroll
    for (int i = 0; i < 2; ++i)
        #pragma unroll
        for (int j = 0; j < 2; ++j)
            #pragma unroll
            for (int r = 0; r < 4; ++r) acc[i][j][r] = 0.f;

    bfrag a_[4][2], b_[2][2];
    #pragma unroll
    for (int ks = 0; ks < 4; ++ks)
        #pragma unroll
        for (int mi = 0; mi < 2; ++mi)
            a_[ks][mi] = *(const bfrag*)(Gs + (size_t)(px0 + mi * 16 + lr) * 512 + ks * 32 + lg * 8);
    #pragma unroll
    for (int nj = 0; nj < 2; ++nj)
        b_[0][nj] = *(const bfrag*)&Bs[(lcb + nj * 16 + lr) * 520 + lg * 8];

    #pragma unroll
    for (int ks = 0; ks < 16; ++ks) {
        if (ks < 15) {
            #pragma unroll
            for (int nj = 0; nj < 2; ++nj)
                b_[(ks + 1) & 1][nj] = *(const bfrag*)&Bs[(lcb + nj * 16 + lr) * 520 + (ks + 1) * 32 + lg * 8];
        }
        if (ks < 12) {
            #pragma unroll
            for (int mi = 0; mi < 2; ++mi)
                a_[(ks + 4) & 3][mi] = *(const bfrag*)(Gs + (size_t)(px0 + mi * 16 + lr) * 512 + (ks + 4) * 32 + lg * 8);
        }
        #pragma unroll
        for (int mi = 0; mi < 2; ++mi)
            #pragma unroll
            for (int nj = 0; nj < 2; ++nj)
                acc[mi][nj] = __builtin_amdgcn_mfma_f32_16x16x32_bf16(a_[ks & 3][mi], b_[ks & 1][nj], acc[mi][nj], 0, 0, 0);
    }

    #pragma unroll
    for (int mi = 0; mi < 2; ++mi)
        #pragma unroll
        for (int nj = 0; nj < 2; ++nj)
            #pragma unroll
            for (int r = 0; r < 4; ++r) {
                const int p = px0 + mi * 16 + lg * 4 + r;
                const int c = c0 + lcb + nj * 16 + lr;
                const int b = p / HW, hw = p % HW;
                const size_t idx = ((size_t)b * C + c) * HW + hw;
                Outp[idx] = __bfloat162float(X1[idx]) + acc[mi][nj][r];
            }
}

extern "C" void kernel_launch(void* const* d_in, const int* in_sizes, int n_in,
                              void* d_out, int out_size, void* d_ws, size_t ws_size,
                              hipStream_t stream) {
    (void)in_sizes; (void)n_in; (void)out_size; (void)ws_size;
    const float* x     = (const float*)d_in[0];
    const float* mask  = (const float*)d_in[1];
    const float* edge  = (const float*)d_in[2];
    const float* ln1w  = (const float*)d_in[3];
    const float* ln1b  = (const float*)d_in[4];
    const float* Wq    = (const float*)d_in[5];
    const float* Wk    = (const float*)d_in[6];
    const float* Wv    = (const float*)d_in[7];
    const float* ln2w  = (const float*)d_in[8];
    const float* ln2b  = (const float*)d_in[9];
    const float* w_in  = (const float*)d_in[10];
    const float* w_dw  = (const float*)d_in[11];
    const float* w_out = (const float*)d_in[12];
    float* out = (float*)d_out;

    char* ws = (char*)d_ws;
    // persistent: [0, 7.93M) x1 bf16 ; [7.93M, 15.86M) xn2 bf16 ;
    // [15.86M, 47.58M) u_half bf16 ; [47.58M, 79.30M) g bf16. Total = 79,298,560 B.
    __hip_bfloat16* x1  = (__hip_bfloat16*)(ws + 0);
    __hip_bfloat16* xn2 = (__hip_bfloat16*)(ws + 7929856);
    __hip_bfloat16* uh  = (__hip_bfloat16*)(ws + 15859712);
    __hip_bfloat16* g   = (__hip_bfloat16*)(ws + 47579136);
    // transient (dead before u_half/g are written):
    __hip_bfloat16* qb  = (__hip_bfloat16*)(ws + 15859712);
    __hip_bfloat16* kb  = (__hip_bfloat16*)(ws + 23789568);
    __hip_bfloat16* vb  = (__hip_bfloat16*)(ws + 31719424);
    __hip_bfloat16* eb  = (__hip_bfloat16*)(ws + 39649280);
    __hip_bfloat16* xnm = (__hip_bfloat16*)(ws + 47579136);

    k_pre<<<968, 256, 0, stream>>>(x, mask, edge, ln1w, ln1b, xnm, eb);
    k_gemmQKV<<<dim3(242, 6), 512, 0, stream>>>(eb, xnm, Wq, Wk, Wv, qb, kb, vb);
    k_attn2<<<968, 512, 0, stream>>>(qb, kb, vb, x, ln2w, ln2b, x1, xn2);
    k_gemm128<<<dim3(242, 8), 512, 0, stream>>>(xn2, w_in, uh, 0);
    k_dw<<<3872, 256, 0, stream>>>(uh, w_dw, g, 0);
    k_gemm128<<<dim3(242, 8), 512, 0, stream>>>(xn2, w_in, uh, 1);
    k_dw<<<3872, 256, 0, stream>>>(uh, w_dw, g, 1);
    k_gemm512<<<dim3(242, 2), 512, 0, stream>>>(g, w_out, x1, out);
}